// Round 1
// baseline (5582.147 us; speedup 1.0000x reference)
//
#include <hip/hip_runtime.h>
#include <hip/hip_bf16.h>

// Problem constants (B=8, T=4096, D=256, K=8192)
#define N_ROWS 32768
#define DDIM   256
#define KCODES 8192
#define BM 64      // rows per block
#define BK 32      // codes per K-tile
#define LDZ 260    // padded LDS stride (floats): bank stride 4 per row-step -> ~2-way
#define LDC 260
#define QZ_ELEMS (N_ROWS * DDIM)   // 8388608 floats of q_z, then indices

// --- codebook squared norms, double accumulation (matches np to ~1e-5) ---
__global__ __launch_bounds__(256) void vq_cnorm(const float* __restrict__ cb,
                                                float* __restrict__ cn) {
  int gid = blockIdx.x * 256 + threadIdx.x;
  int w = gid >> 6;        // codebook row (one wave per row)
  int lane = gid & 63;     // 64 lanes x 4 floats = 256 = D
  float4 c4 = *reinterpret_cast<const float4*>(cb + (size_t)w * DDIM + lane * 4);
  double s = (double)c4.x * c4.x + (double)c4.y * c4.y +
             (double)c4.z * c4.z + (double)c4.w * c4.w;
  #pragma unroll
  for (int off = 32; off > 0; off >>= 1) s += __shfl_down(s, off, 64);
  if (lane == 0) cn[w] = (float)s;
}

// --- fused distance-argmin + gather ---
// block: 256 threads, owns BM=64 rows. Streams all K codes in BK=32 tiles.
// thread (tr = t>>4, tc = t&15): rows 4*tr..4*tr+3, codes {kt+tc, kt+tc+16}.
__global__ __launch_bounds__(256) void vq_main(const float* __restrict__ z,
                                               const float* __restrict__ cb,
                                               const float* __restrict__ cn,
                                               float* __restrict__ out) {
  __shared__ float zs[BM * LDZ];
  __shared__ float cs[BK * LDC];
  __shared__ float redd[BM][16];
  __shared__ int   redi[BM][16];
  __shared__ int   sidx[BM];

  const int t = threadIdx.x;
  const int row0 = blockIdx.x * BM;

  // stage z tile: 64 rows x 64 float4; each wave-instruction covers one row
  #pragma unroll
  for (int i = 0; i < 16; ++i) {
    int f = t + i * 256;
    int r = f >> 6, c4 = f & 63;
    float4 v = *reinterpret_cast<const float4*>(z + (size_t)(row0 + r) * DDIM + c4 * 4);
    *reinterpret_cast<float4*>(&zs[r * LDZ + c4 * 4]) = v;
  }

  const int tr = t >> 4;   // 0..15 -> 4 rows each
  const int tc = t & 15;   // 0..15 -> codes tc, tc+16 within tile

  float best[4];
  int   bidx[4];
  #pragma unroll
  for (int i = 0; i < 4; ++i) { best[i] = 3.4e38f; bidx[i] = 0; }

  for (int kt = 0; kt < KCODES; kt += BK) {
    __syncthreads();   // previous tile's cs reads done (also covers zs staging)
    // stage codebook tile: 32 rows x 64 float4, coalesced
    #pragma unroll
    for (int i = 0; i < 8; ++i) {
      int f = t + i * 256;
      int r = f >> 6, c4 = f & 63;
      float4 v = *reinterpret_cast<const float4*>(cb + (size_t)(kt + r) * DDIM + c4 * 4);
      *reinterpret_cast<float4*>(&cs[r * LDC + c4 * 4]) = v;
    }
    __syncthreads();

    float acc[4][2] = {{0.f,0.f},{0.f,0.f},{0.f,0.f},{0.f,0.f}};
    #pragma unroll 8
    for (int d4 = 0; d4 < 64; ++d4) {
      float4 b0 = *reinterpret_cast<const float4*>(&cs[tc * LDC + d4 * 4]);
      float4 b1 = *reinterpret_cast<const float4*>(&cs[(tc + 16) * LDC + d4 * 4]);
      #pragma unroll
      for (int i = 0; i < 4; ++i) {
        float4 a = *reinterpret_cast<const float4*>(&zs[(4 * tr + i) * LDZ + d4 * 4]);
        acc[i][0] = fmaf(a.x, b0.x, acc[i][0]);
        acc[i][0] = fmaf(a.y, b0.y, acc[i][0]);
        acc[i][0] = fmaf(a.z, b0.z, acc[i][0]);
        acc[i][0] = fmaf(a.w, b0.w, acc[i][0]);
        acc[i][1] = fmaf(a.x, b1.x, acc[i][1]);
        acc[i][1] = fmaf(a.y, b1.y, acc[i][1]);
        acc[i][1] = fmaf(a.z, b1.z, acc[i][1]);
        acc[i][1] = fmaf(a.w, b1.w, acc[i][1]);
      }
    }

    // dist = ||c||^2 - 2*dot  (||z||^2 constant per row -> dropped)
    float cn0 = cn[kt + tc];
    float cn1 = cn[kt + tc + 16];
    #pragma unroll
    for (int i = 0; i < 4; ++i) {
      float d0 = cn0 - 2.0f * acc[i][0];
      if (d0 < best[i]) { best[i] = d0; bidx[i] = kt + tc; }        // strict < : first-min
      float d1 = cn1 - 2.0f * acc[i][1];
      if (d1 < best[i]) { best[i] = d1; bidx[i] = kt + tc + 16; }
    }
  }

  // cross-thread (16 tc-groups) argmin reduction per row
  #pragma unroll
  for (int i = 0; i < 4; ++i) {
    redd[4 * tr + i][tc] = best[i];
    redi[4 * tr + i][tc] = bidx[i];
  }
  __syncthreads();
  if (t < BM) {
    float bd = redd[t][0];
    int   bi = redi[t][0];
    #pragma unroll
    for (int j = 1; j < 16; ++j) {
      float d = redd[t][j];
      int   ix = redi[t][j];
      if (d < bd || (d == bd && ix < bi)) { bd = d; bi = ix; }  // np first-min tie-break
    }
    sidx[t] = bi;
    out[QZ_ELEMS + row0 + t] = (float)bi;   // indices stored as float values
  }
  __syncthreads();

  // gather q_z = codebook[idx] for this block's rows (codebook is L2/LLC hot)
  #pragma unroll
  for (int i = 0; i < 16; ++i) {
    int f = t + i * 256;
    int r = f >> 6, c4 = f & 63;
    float4 v = *reinterpret_cast<const float4*>(cb + (size_t)sidx[r] * DDIM + c4 * 4);
    *reinterpret_cast<float4*>(&out[(size_t)(row0 + r) * DDIM + c4 * 4]) = v;
  }
}

extern "C" void kernel_launch(void* const* d_in, const int* in_sizes, int n_in,
                              void* d_out, int out_size, void* d_ws, size_t ws_size,
                              hipStream_t stream) {
  const float* z  = (const float*)d_in[0];
  const float* cb = (const float*)d_in[1];
  float* out = (float*)d_out;
  float* cn  = (float*)d_ws;   // 8192 floats of scratch

  vq_cnorm<<<(KCODES * 64) / 256, 256, 0, stream>>>(cb, cn);
  vq_main<<<N_ROWS / BM, 256, 0, stream>>>(z, cb, cn, out);
}

// Round 2
// 771.104 us; speedup vs baseline: 7.2392x; 7.2392x over previous
//
#include <hip/hip_runtime.h>
#include <hip/hip_bf16.h>

#define N_ROWS 32768
#define DDIM   256
#define KCODES 8192
#define QZ_ELEMS (N_ROWS * DDIM)
#define NTILES 128
#define MARGIN 0.03125f

typedef __attribute__((ext_vector_type(8))) short short8;
typedef __attribute__((ext_vector_type(4))) float f32x4;

__device__ __forceinline__ unsigned short f2bf(float f) {
  unsigned u = __builtin_bit_cast(unsigned, f);
  u += 0x7FFFu + ((u >> 16) & 1u);
  return (unsigned short)(u >> 16);
}
__device__ __forceinline__ float bf2f(unsigned short h) {
  unsigned u = ((unsigned)h) << 16;
  return __builtin_bit_cast(float, u);
}

// ---- cnorm only (double accumulation; used by both paths) ----
__global__ __launch_bounds__(256) void vq_cnorm(const float* __restrict__ cb,
                                                float* __restrict__ cn) {
  int n = blockIdx.x * 4 + (threadIdx.x >> 6);
  int lane = threadIdx.x & 63;
  float4 c4 = *reinterpret_cast<const float4*>(cb + (size_t)n * DDIM + lane * 4);
  double s = (double)c4.x * c4.x + (double)c4.y * c4.y +
             (double)c4.z * c4.z + (double)c4.w * c4.w;
  #pragma unroll
  for (int off = 32; off > 0; off >>= 1) s += __shfl_down(s, off, 64);
  if (lane == 0) cn[n] = (float)s;
}

// ---- prep: codebook -> swizzled bf16 hi|lo (1 KB/code) + cnorm ----
__global__ __launch_bounds__(256) void vq_prep(const float* __restrict__ cb,
                                               unsigned char* __restrict__ wcb,
                                               float* __restrict__ cn) {
  int n = blockIdx.x * 4 + (threadIdx.x >> 6);
  int lane = threadIdx.x & 63;
  float4 c4 = *reinterpret_cast<const float4*>(cb + (size_t)n * DDIM + lane * 4);
  double s = (double)c4.x * c4.x + (double)c4.y * c4.y +
             (double)c4.z * c4.z + (double)c4.w * c4.w;
  #pragma unroll
  for (int off = 32; off > 0; off >>= 1) s += __shfl_down(s, off, 64);
  if (lane == 0) cn[n] = (float)s;

  float xs[4] = {c4.x, c4.y, c4.z, c4.w};
  unsigned short h[4], l[4];
  #pragma unroll
  for (int j = 0; j < 4; ++j) {
    h[j] = f2bf(xs[j]);
    l[j] = f2bf(xs[j] - bf2f(h[j]));
  }
  size_t base = (size_t)n * 1024 +
                (size_t)(((((lane >> 1) ^ (n & 7))) << 4) + (lane & 1) * 8);
  *reinterpret_cast<ushort4*>(wcb + base)       = make_ushort4(h[0], h[1], h[2], h[3]);
  *reinterpret_cast<ushort4*>(wcb + base + 512) = make_ushort4(l[0], l[1], l[2], l[3]);
}

// ---- main MFMA kernel ----
__global__ __launch_bounds__(512, 2) void vq_mfma(
    const float* __restrict__ z, const unsigned char* __restrict__ wcb,
    const float* __restrict__ cn, const float* __restrict__ cb,
    float* __restrict__ out, int* __restrict__ flagCnt, int* __restrict__ flagRows) {
  __shared__ __align__(16) unsigned char lds[2][65536];
  __shared__ float sB[2][128], sS[2][128];
  __shared__ int sI[2][128], sIdx[128];

  const int tid = threadIdx.x;
  const int w = tid >> 6, lane = tid & 63;
  const int wm = w >> 1, wn = w & 1;
  const int g = lane >> 4, l15 = lane & 15;
  const int rowA = blockIdx.x * 128 + wm * 32 + l15;

  short8 zh[2][8], zl[2][8];
  #pragma unroll
  for (int mf = 0; mf < 2; ++mf) {
    #pragma unroll
    for (int dc = 0; dc < 8; ++dc) {
      const float* zp = z + (size_t)(rowA + mf * 16) * DDIM + dc * 32 + g * 8;
      float4 f0 = *reinterpret_cast<const float4*>(zp);
      float4 f1 = *reinterpret_cast<const float4*>(zp + 4);
      float xs[8] = {f0.x, f0.y, f0.z, f0.w, f1.x, f1.y, f1.z, f1.w};
      short8 hh, ll;
      #pragma unroll
      for (int j = 0; j < 8; ++j) {
        unsigned short hb = f2bf(xs[j]);
        hh[j] = (short)hb;
        ll[j] = (short)f2bf(xs[j] - bf2f(hb));
      }
      zh[mf][dc] = hh; zl[mf][dc] = ll;
    }
  }

  float best[8], secd[8];
  int bidx[8];
  #pragma unroll
  for (int s = 0; s < 8; ++s) { best[s] = 3.4e38f; secd[s] = 3.4e38f; bidx[s] = 0; }

  const float* cnp = cn + wn * 32 + l15;
  const int r0 = wn * 32 + l15;
  const int r1 = r0 + 16;
  const int sw = (r0 & 7) << 4;

  #pragma unroll
  for (int i = 0; i < 8; ++i) {
    int c = (w << 3) + i;
    __builtin_amdgcn_global_load_lds(
        (const __attribute__((address_space(1))) void*)(wcb + c * 1024 + lane * 16),
        (__attribute__((address_space(3))) void*)(&lds[0][c * 1024]), 16, 0, 0);
  }
  __syncthreads();

  for (int nt = 0; nt < NTILES; ++nt) {
    const int cur = nt & 1;
    if (nt + 1 < NTILES) {
      const unsigned char* gsrc = wcb + (size_t)(nt + 1) * 65536;
      #pragma unroll
      for (int i = 0; i < 8; ++i) {
        int c = (w << 3) + i;
        __builtin_amdgcn_global_load_lds(
            (const __attribute__((address_space(1))) void*)(gsrc + c * 1024 + lane * 16),
            (__attribute__((address_space(3))) void*)(&lds[cur ^ 1][c * 1024]), 16, 0, 0);
      }
    }

    const unsigned char* lb = lds[cur];
    f32x4 a00 = {0.f, 0.f, 0.f, 0.f}, a01 = a00, a10 = a00, a11 = a00;
    #pragma unroll
    for (int dc = 0; dc < 8; ++dc) {
      int ub = (dc * 4 + g) << 4;
      int o0 = r0 * 1024 + (ub ^ sw);
      int o1 = r1 * 1024 + (ub ^ sw);
      short8 ch0 = *reinterpret_cast<const short8*>(lb + o0);
      short8 cl0 = *reinterpret_cast<const short8*>(lb + o0 + 512);
      short8 ch1 = *reinterpret_cast<const short8*>(lb + o1);
      short8 cl1 = *reinterpret_cast<const short8*>(lb + o1 + 512);
      a00 = __builtin_amdgcn_mfma_f32_16x16x32_bf16(zh[0][dc], ch0, a00, 0, 0, 0);
      a10 = __builtin_amdgcn_mfma_f32_16x16x32_bf16(zh[1][dc], ch0, a10, 0, 0, 0);
      a01 = __builtin_amdgcn_mfma_f32_16x16x32_bf16(zh[0][dc], ch1, a01, 0, 0, 0);
      a11 = __builtin_amdgcn_mfma_f32_16x16x32_bf16(zh[1][dc], ch1, a11, 0, 0, 0);
      a00 = __builtin_amdgcn_mfma_f32_16x16x32_bf16(zl[0][dc], ch0, a00, 0, 0, 0);
      a10 = __builtin_amdgcn_mfma_f32_16x16x32_bf16(zl[1][dc], ch0, a10, 0, 0, 0);
      a01 = __builtin_amdgcn_mfma_f32_16x16x32_bf16(zl[0][dc], ch1, a01, 0, 0, 0);
      a11 = __builtin_amdgcn_mfma_f32_16x16x32_bf16(zl[1][dc], ch1, a11, 0, 0, 0);
      a00 = __builtin_amdgcn_mfma_f32_16x16x32_bf16(zh[0][dc], cl0, a00, 0, 0, 0);
      a10 = __builtin_amdgcn_mfma_f32_16x16x32_bf16(zh[1][dc], cl0, a10, 0, 0, 0);
      a01 = __builtin_amdgcn_mfma_f32_16x16x32_bf16(zh[0][dc], cl1, a01, 0, 0, 0);
      a11 = __builtin_amdgcn_mfma_f32_16x16x32_bf16(zh[1][dc], cl1, a11, 0, 0, 0);
    }

    float cn0 = cnp[nt * 64];
    float cn1 = cnp[nt * 64 + 16];
    int code0 = nt * 64 + wn * 32 + l15;
    #pragma unroll
    for (int mf = 0; mf < 2; ++mf) {
      const f32x4 an0 = mf ? a10 : a00;
      const f32x4 an1 = mf ? a11 : a01;
      #pragma unroll
      for (int r = 0; r < 4; ++r) {
        int s = mf * 4 + r;
        float d0 = cn0 - 2.0f * an0[r];
        if (d0 < best[s]) { secd[s] = best[s]; best[s] = d0; bidx[s] = code0; }
        else if (d0 < secd[s]) secd[s] = d0;
        float d1 = cn1 - 2.0f * an1[r];
        if (d1 < best[s]) { secd[s] = best[s]; best[s] = d1; bidx[s] = code0 + 16; }
        else if (d1 < secd[s]) secd[s] = d1;
      }
    }
    __syncthreads();
  }

  #pragma unroll
  for (int s = 0; s < 8; ++s) {
    float b = best[s], sc = secd[s];
    int ix = bidx[s];
    #pragma unroll
    for (int m = 1; m <= 8; m <<= 1) {
      float ob = __shfl_xor(b, m, 64);
      float os = __shfl_xor(sc, m, 64);
      int   oi = __shfl_xor(ix, m, 64);
      if (ob < b) { sc = fminf(b, os); b = ob; ix = oi; }
      else { if (ob == b && oi < ix) ix = oi; sc = fminf(sc, ob); }
    }
    if (l15 == 0) {
      int row = wm * 32 + (s >> 2) * 16 + g * 4 + (s & 3);
      sB[wn][row] = b; sS[wn][row] = sc; sI[wn][row] = ix;
    }
  }
  __syncthreads();

  if (tid < 128) {
    float b0 = sB[0][tid], s0 = sS[0][tid];
    float b1 = sB[1][tid], s1 = sS[1][tid];
    int i0 = sI[0][tid], i1 = sI[1][tid];
    float nb, ns; int ni;
    if (b1 < b0) { nb = b1; ni = i1; ns = fminf(b0, s1); }
    else { nb = b0; ni = i0; if (b1 == b0 && i1 < i0) ni = i1; ns = fminf(s0, b1); }
    int grow = blockIdx.x * 128 + tid;
    out[QZ_ELEMS + grow] = (float)ni;
    sIdx[tid] = ni;
    if (ns - nb < MARGIN) { int p = atomicAdd(flagCnt, 1); flagRows[p] = grow; }
  }
  __syncthreads();

  #pragma unroll
  for (int i = 0; i < 16; ++i) {
    int f = tid + i * 512;
    int r = f >> 6, c4 = f & 63;
    float4 v = *reinterpret_cast<const float4*>(cb + (size_t)sIdx[r] * DDIM + c4 * 4);
    *reinterpret_cast<float4*>(&out[(size_t)(blockIdx.x * 128 + r) * DDIM + c4 * 4]) = v;
  }
}

// ---- cleanup: exact fp32 recheck for flagged rows ----
__global__ __launch_bounds__(256) void vq_cleanup(
    const float* __restrict__ z, const float* __restrict__ cb,
    const float* __restrict__ cn, float* __restrict__ out,
    const int* __restrict__ flagCnt, const int* __restrict__ flagRows) {
  __shared__ float zrow[DDIM];
  __shared__ unsigned long long wred[4];
  __shared__ int skmin;
  int nflag = *flagCnt;
  for (int fi = blockIdx.x; fi < nflag; fi += gridDim.x) {
    int row = flagRows[fi];
    __syncthreads();
    if (threadIdx.x < 64)
      *reinterpret_cast<float4*>(&zrow[threadIdx.x * 4]) =
          *reinterpret_cast<const float4*>(z + (size_t)row * DDIM + threadIdx.x * 4);
    __syncthreads();
    unsigned long long bkey = ~0ULL;
    for (int j = 0; j < 32; ++j) {
      int k = threadIdx.x + j * 256;
      const float* cp = cb + (size_t)k * DDIM;
      float acc = 0.f;
      #pragma unroll 8
      for (int d4 = 0; d4 < 64; ++d4) {
        float4 a = *reinterpret_cast<const float4*>(&zrow[d4 * 4]);
        float4 c4 = *reinterpret_cast<const float4*>(cp + d4 * 4);
        acc = fmaf(a.x, c4.x, acc); acc = fmaf(a.y, c4.y, acc);
        acc = fmaf(a.z, c4.z, acc); acc = fmaf(a.w, c4.w, acc);
      }
      float d = cn[k] - 2.0f * acc;
      unsigned m = __builtin_bit_cast(unsigned, d);
      m = (m >> 31) ? ~m : (m | 0x80000000u);
      unsigned long long key = ((unsigned long long)m << 32) | (unsigned)k;
      bkey = (key < bkey) ? key : bkey;
    }
    #pragma unroll
    for (int m2 = 1; m2 <= 32; m2 <<= 1) {
      unsigned long long o = __shfl_xor(bkey, m2, 64);
      bkey = (o < bkey) ? o : bkey;
    }
    if ((threadIdx.x & 63) == 0) wred[threadIdx.x >> 6] = bkey;
    __syncthreads();
    if (threadIdx.x == 0) {
      unsigned long long kk = wred[0];
      for (int q = 1; q < 4; ++q) kk = (wred[q] < kk) ? wred[q] : kk;
      int ki = (int)(kk & 0xFFFFFFFFULL);
      skmin = ki;
      out[QZ_ELEMS + row] = (float)ki;
    }
    __syncthreads();
    int ki = skmin;
    if (threadIdx.x < 64)
      *reinterpret_cast<float4*>(&out[(size_t)row * DDIM + threadIdx.x * 4]) =
          *reinterpret_cast<const float4*>(cb + (size_t)ki * DDIM + threadIdx.x * 4);
    __syncthreads();
  }
}

// ---- round-1 fp32 fallback ----
#define FB_BM 64
#define FB_BK 32
#define FB_LD 260
__global__ __launch_bounds__(256) void vq_main_fb(const float* __restrict__ z,
                                                  const float* __restrict__ cb,
                                                  const float* __restrict__ cn,
                                                  float* __restrict__ out) {
  __shared__ float zs[FB_BM * FB_LD];
  __shared__ float cs[FB_BK * FB_LD];
  __shared__ float redd[FB_BM][16];
  __shared__ int   redi[FB_BM][16];
  __shared__ int   sidx[FB_BM];
  const int t = threadIdx.x;
  const int row0 = blockIdx.x * FB_BM;
  #pragma unroll
  for (int i = 0; i < 16; ++i) {
    int f = t + i * 256; int r = f >> 6, c4 = f & 63;
    *reinterpret_cast<float4*>(&zs[r * FB_LD + c4 * 4]) =
        *reinterpret_cast<const float4*>(z + (size_t)(row0 + r) * DDIM + c4 * 4);
  }
  const int tr = t >> 4, tc = t & 15;
  float best[4]; int bidx[4];
  #pragma unroll
  for (int i = 0; i < 4; ++i) { best[i] = 3.4e38f; bidx[i] = 0; }
  for (int kt = 0; kt < KCODES; kt += FB_BK) {
    __syncthreads();
    #pragma unroll
    for (int i = 0; i < 8; ++i) {
      int f = t + i * 256; int r = f >> 6, c4 = f & 63;
      *reinterpret_cast<float4*>(&cs[r * FB_LD + c4 * 4]) =
          *reinterpret_cast<const float4*>(cb + (size_t)(kt + r) * DDIM + c4 * 4);
    }
    __syncthreads();
    float acc[4][2] = {{0.f,0.f},{0.f,0.f},{0.f,0.f},{0.f,0.f}};
    #pragma unroll 8
    for (int d4 = 0; d4 < 64; ++d4) {
      float4 b0 = *reinterpret_cast<const float4*>(&cs[tc * FB_LD + d4 * 4]);
      float4 b1 = *reinterpret_cast<const float4*>(&cs[(tc + 16) * FB_LD + d4 * 4]);
      #pragma unroll
      for (int i = 0; i < 4; ++i) {
        float4 a = *reinterpret_cast<const float4*>(&zs[(4 * tr + i) * FB_LD + d4 * 4]);
        acc[i][0] = fmaf(a.x, b0.x, acc[i][0]); acc[i][0] = fmaf(a.y, b0.y, acc[i][0]);
        acc[i][0] = fmaf(a.z, b0.z, acc[i][0]); acc[i][0] = fmaf(a.w, b0.w, acc[i][0]);
        acc[i][1] = fmaf(a.x, b1.x, acc[i][1]); acc[i][1] = fmaf(a.y, b1.y, acc[i][1]);
        acc[i][1] = fmaf(a.z, b1.z, acc[i][1]); acc[i][1] = fmaf(a.w, b1.w, acc[i][1]);
      }
    }
    float cn0 = cn[kt + tc], cn1 = cn[kt + tc + 16];
    #pragma unroll
    for (int i = 0; i < 4; ++i) {
      float d0 = cn0 - 2.0f * acc[i][0];
      if (d0 < best[i]) { best[i] = d0; bidx[i] = kt + tc; }
      float d1 = cn1 - 2.0f * acc[i][1];
      if (d1 < best[i]) { best[i] = d1; bidx[i] = kt + tc + 16; }
    }
  }
  #pragma unroll
  for (int i = 0; i < 4; ++i) { redd[4 * tr + i][tc] = best[i]; redi[4 * tr + i][tc] = bidx[i]; }
  __syncthreads();
  if (t < FB_BM) {
    float bd = redd[t][0]; int bi = redi[t][0];
    #pragma unroll
    for (int j = 1; j < 16; ++j) {
      float d = redd[t][j]; int ix = redi[t][j];
      if (d < bd || (d == bd && ix < bi)) { bd = d; bi = ix; }
    }
    sidx[t] = bi;
    out[QZ_ELEMS + row0 + t] = (float)bi;
  }
  __syncthreads();
  #pragma unroll
  for (int i = 0; i < 16; ++i) {
    int f = t + i * 256; int r = f >> 6, c4 = f & 63;
    *reinterpret_cast<float4*>(&out[(size_t)(row0 + r) * DDIM + c4 * 4]) =
        *reinterpret_cast<const float4*>(cb + (size_t)sidx[r] * DDIM + c4 * 4);
  }
}

extern "C" void kernel_launch(void* const* d_in, const int* in_sizes, int n_in,
                              void* d_out, int out_size, void* d_ws, size_t ws_size,
                              hipStream_t stream) {
  const float* z  = (const float*)d_in[0];
  const float* cb = (const float*)d_in[1];
  float* out = (float*)d_out;

  const size_t CB_BYTES = (size_t)KCODES * 1024;
  const size_t CN_OFF   = CB_BYTES;
  const size_t FC_OFF   = CN_OFF + (size_t)KCODES * 4 + 224;
  const size_t FR_OFF   = FC_OFF + 16;
  const size_t NEED     = FR_OFF + (size_t)N_ROWS * 4;

  if (ws_size >= NEED) {
    unsigned char* wcb = (unsigned char*)d_ws;
    float* cn = (float*)(wcb + CN_OFF);
    int* flagCnt = (int*)(wcb + FC_OFF);
    int* flagRows = (int*)(wcb + FR_OFF);
    hipMemsetAsync(flagCnt, 0, 4, stream);
    vq_prep<<<KCODES / 4, 256, 0, stream>>>(cb, wcb, cn);
    vq_mfma<<<N_ROWS / 128, 512, 0, stream>>>(z, wcb, cn, cb, out, flagCnt, flagRows);
    vq_cleanup<<<128, 256, 0, stream>>>(z, cb, cn, out, flagCnt, flagRows);
  } else {
    float* cn = (float*)d_ws;
    vq_cnorm<<<KCODES / 4, 256, 0, stream>>>(cb, cn);
    vq_main_fb<<<N_ROWS / FB_BM, 256, 0, stream>>>(z, cb, cn, out);
  }
}